// Round 1
// baseline (593.753 us; speedup 1.0000x reference)
//
#include <hip/hip_runtime.h>
#include <hip/hip_bf16.h>

typedef unsigned short u16;
typedef __attribute__((ext_vector_type(8))) __bf16 bf16x8;
typedef __attribute__((ext_vector_type(4))) float f32x4;

#define LOG2E 1.44269504088896340736f

__device__ __forceinline__ u16 f2bf(float f) {
  union { float f; unsigned u; } v; v.f = f;
  unsigned r = v.u + 0x7fffu + ((v.u >> 16) & 1u);
  return (u16)(r >> 16);
}

// ---------------- kernel: hidden_states fp32 -> bf16 ----------------
__global__ __launch_bounds__(256) void k_cvtX(const float* __restrict__ x,
                                              u16* __restrict__ xb) {
  int i = (blockIdx.x * 256 + threadIdx.x) * 4;
  float4 v = *reinterpret_cast<const float4*>(x + i);
  ushort4 o;
  o.x = f2bf(v.x); o.y = f2bf(v.y); o.z = f2bf(v.z); o.w = f2bf(v.w);
  *reinterpret_cast<ushort4*>(xb + i) = o;
}

// ---------------- kernel: W fp32 [K][N] -> Wt bf16 [N][K] ----------------
__global__ __launch_bounds__(256) void k_cvtW(const float* __restrict__ Wq,
                                              const float* __restrict__ Wk,
                                              const float* __restrict__ Wv,
                                              u16* __restrict__ Wtq,
                                              u16* __restrict__ Wtk,
                                              u16* __restrict__ Wtv) {
  const float* W = blockIdx.z == 0 ? Wq : (blockIdx.z == 1 ? Wk : Wv);
  u16* Wt = blockIdx.z == 0 ? Wtq : (blockIdx.z == 1 ? Wtk : Wtv);
  __shared__ u16 t[64][65];
  int n0 = blockIdx.x * 64, k0 = blockIdx.y * 64;
  int tid = threadIdx.x;
#pragma unroll
  for (int it = 0; it < 4; ++it) {
    int idx = it * 256 + tid;
    int r = idx >> 4, c = (idx & 15) * 4;   // r: k-local row, c: n-local col
    float4 v = *reinterpret_cast<const float4*>(W + (size_t)(k0 + r) * 1024 + n0 + c);
    t[r][c] = f2bf(v.x); t[r][c + 1] = f2bf(v.y);
    t[r][c + 2] = f2bf(v.z); t[r][c + 3] = f2bf(v.w);
  }
  __syncthreads();
#pragma unroll
  for (int it = 0; it < 4; ++it) {
    int idx = it * 256 + tid;
    int r = idx >> 4, c = (idx & 15) * 4;   // r: n-local row, c: k-local col
    ushort4 o;
    o.x = t[c][r]; o.y = t[c + 1][r]; o.z = t[c + 2][r]; o.w = t[c + 3][r];
    *reinterpret_cast<ushort4*>(Wt + (size_t)(n0 + r) * 1024 + k0 + c) = o;
  }
}

// ---------------- kernel: QKV projection GEMM ----------------
// C[8192,1024] = Xb[8192,1024] @ W[1024,1024] + b  -> bf16 [B,H,S,D]
// z selects Q/K/V. Q gets fused scale 0.125*log2(e) (softmax in exp2 domain).
__global__ __launch_bounds__(256) void k_qkv(
    const u16* __restrict__ Xb,
    const u16* __restrict__ Wtq, const u16* __restrict__ Wtk, const u16* __restrict__ Wtv,
    const float* __restrict__ bq, const float* __restrict__ bk, const float* __restrict__ bv,
    u16* __restrict__ Qb, u16* __restrict__ Kb, u16* __restrict__ Vb) {
  int z = blockIdx.z;
  const u16* Wt = z == 0 ? Wtq : (z == 1 ? Wtk : Wtv);
  const float* bias = z == 0 ? bq : (z == 1 ? bk : bv);
  u16* Out = z == 0 ? Qb : (z == 1 ? Kb : Vb);
  float scale = z == 0 ? 0.125f * LOG2E : 1.0f;

  __shared__ u16 Ash[128 * 32];   // [m 128][k 32], 64B rows -> conflict-free b128 frags
  __shared__ u16 Bsh[128 * 32];   // [n 128][k 32]

  int tid = threadIdx.x;
  int w = tid >> 6, lane = tid & 63;
  int r16 = lane & 15, g4 = lane >> 4;
  int wm = w >> 1, wn = w & 1;
  int m0 = blockIdx.y * 128, n0 = blockIdx.x * 128;

  f32x4 zero = {0.f, 0.f, 0.f, 0.f};
  f32x4 acc[4][4];
#pragma unroll
  for (int i = 0; i < 4; ++i)
#pragma unroll
    for (int j = 0; j < 4; ++j) acc[i][j] = zero;

  uint4 ar[2], br[2];
#pragma unroll
  for (int c = 0; c < 2; ++c) {           // prefetch kt=0
    int idx = c * 256 + tid;
    int row = idx >> 2, c4 = idx & 3;
    ar[c] = *reinterpret_cast<const uint4*>(Xb + (size_t)(m0 + row) * 1024 + c4 * 8);
    br[c] = *reinterpret_cast<const uint4*>(Wt + (size_t)(n0 + row) * 1024 + c4 * 8);
  }

  for (int kt = 0; kt < 32; ++kt) {
    __syncthreads();
#pragma unroll
    for (int c = 0; c < 2; ++c) {
      int idx = c * 256 + tid;
      int row = idx >> 2, c4 = idx & 3;
      *reinterpret_cast<uint4*>(Ash + row * 32 + c4 * 8) = ar[c];
      *reinterpret_cast<uint4*>(Bsh + row * 32 + c4 * 8) = br[c];
    }
    __syncthreads();
    if (kt < 31) {                        // prefetch next K-tile under MFMA
      int k0n = (kt + 1) * 32;
#pragma unroll
      for (int c = 0; c < 2; ++c) {
        int idx = c * 256 + tid;
        int row = idx >> 2, c4 = idx & 3;
        ar[c] = *reinterpret_cast<const uint4*>(Xb + (size_t)(m0 + row) * 1024 + k0n + c4 * 8);
        br[c] = *reinterpret_cast<const uint4*>(Wt + (size_t)(n0 + row) * 1024 + k0n + c4 * 8);
      }
    }
    bf16x8 af[4], bfr[4];
#pragma unroll
    for (int mi = 0; mi < 4; ++mi)
      af[mi] = *reinterpret_cast<const bf16x8*>(Ash + (wm * 64 + mi * 16 + r16) * 32 + g4 * 8);
#pragma unroll
    for (int ni = 0; ni < 4; ++ni)
      bfr[ni] = *reinterpret_cast<const bf16x8*>(Bsh + (wn * 64 + ni * 16 + r16) * 32 + g4 * 8);
#pragma unroll
    for (int mi = 0; mi < 4; ++mi)
#pragma unroll
      for (int ni = 0; ni < 4; ++ni)
        acc[mi][ni] = __builtin_amdgcn_mfma_f32_16x16x32_bf16(af[mi], bfr[ni], acc[mi][ni], 0, 0, 0);
  }

  // epilogue: +bias, *scale, bf16, scatter into [b,h,s,d]
#pragma unroll
  for (int ni = 0; ni < 4; ++ni) {
    int n = n0 + wn * 64 + ni * 16 + r16;
    float bv_ = bias[n];
    int h = n >> 6, d = n & 63;
#pragma unroll
    for (int mi = 0; mi < 4; ++mi) {
#pragma unroll
      for (int j = 0; j < 4; ++j) {
        int mrow = m0 + wm * 64 + mi * 16 + g4 * 4 + j;
        int b = mrow >> 11, s = mrow & 2047;
        float val = (acc[mi][ni][j] + bv_) * scale;
        Out[(size_t)((b * 16 + h) * 2048 + s) * 64 + d] = f2bf(val);
      }
    }
  }
}

// ---------------- kernel: flash attention ----------------
// grid = 64 (b*h) * 16 (q-tiles of 128). block = 256 (4 waves x 32 q-rows).
__global__ __launch_bounds__(256) void k_attn(
    const u16* __restrict__ Qb, const u16* __restrict__ Kb,
    const u16* __restrict__ Vb, float* __restrict__ out) {
  int bh = blockIdx.x >> 4, qt = blockIdx.x & 15;
  const u16* Qp = Qb + (size_t)bh * 2048 * 64 + qt * 128 * 64;
  const u16* Kp = Kb + (size_t)bh * 2048 * 64;
  const u16* Vp = Vb + (size_t)bh * 2048 * 64;

  int tid = threadIdx.x;
  int w = tid >> 6, lane = tid & 63;
  int r16 = lane & 15, g4 = lane >> 4;

  __shared__ u16 Ksh[2][64][32];        // [d-half][key][d%32]  64B rows
  __shared__ u16 Vsh[2][64][32];        // [key-half][d][key%32] (V^T) 64B rows
  __shared__ u16 Psh[4][2][32][32];     // [wave][key-half][q][key%32]

  bf16x8 qf[2][2];                      // Q held in registers, pre-scaled
#pragma unroll
  for (int rt = 0; rt < 2; ++rt)
#pragma unroll
    for (int ks = 0; ks < 2; ++ks)
      qf[rt][ks] = *reinterpret_cast<const bf16x8*>(
          Qp + (w * 32 + rt * 16 + r16) * 64 + ks * 32 + g4 * 8);

  f32x4 zero = {0.f, 0.f, 0.f, 0.f};
  f32x4 o[2][4];
  float m[2][4], l[2][4];
#pragma unroll
  for (int rt = 0; rt < 2; ++rt) {
#pragma unroll
    for (int cf = 0; cf < 4; ++cf) o[rt][cf] = zero;
#pragma unroll
    for (int j = 0; j < 4; ++j) { m[rt][j] = -1e30f; l[rt][j] = 0.f; }
  }

  uint4 kr[2], vr[2];
#pragma unroll
  for (int c = 0; c < 2; ++c) {         // prefetch kt=0
    int idx = c * 256 + tid;
    int c4 = idx & 3, key = (idx >> 2) & 63, ks = idx >> 8;
    kr[c] = *reinterpret_cast<const uint4*>(Kp + (key) * 64 + ks * 32 + c4 * 8);
    int dc = c * 4 + w;
    vr[c] = *reinterpret_cast<const uint4*>(Vp + (lane) * 64 + dc * 8);
  }

  for (int kt = 0; kt < 32; ++kt) {
    __syncthreads();
#pragma unroll
    for (int c = 0; c < 2; ++c) {       // stage K (b128) + V transposed (b16 x8)
      int idx = c * 256 + tid;
      int c4 = idx & 3, key = (idx >> 2) & 63, ks = idx >> 8;
      *reinterpret_cast<uint4*>(&Ksh[ks][key][c4 * 8]) = kr[c];
      int dc = c * 4 + w;
      const u16* pv = reinterpret_cast<const u16*>(&vr[c]);
#pragma unroll
      for (int i = 0; i < 8; ++i)
        Vsh[lane >> 5][dc * 8 + i][lane & 31] = pv[i];
    }
    __syncthreads();
    if (kt < 31) {                      // prefetch next tile under compute
      int key0 = (kt + 1) * 64;
#pragma unroll
      for (int c = 0; c < 2; ++c) {
        int idx = c * 256 + tid;
        int c4 = idx & 3, key = (idx >> 2) & 63, ks = idx >> 8;
        kr[c] = *reinterpret_cast<const uint4*>(Kp + (key0 + key) * 64 + ks * 32 + c4 * 8);
        int dc = c * 4 + w;
        vr[c] = *reinterpret_cast<const uint4*>(Vp + (key0 + lane) * 64 + dc * 8);
      }
    }

    // ---- scores: S = Q K^T (exp2 domain via pre-scaled Q) ----
    f32x4 s[2][4];
#pragma unroll
    for (int rt = 0; rt < 2; ++rt)
#pragma unroll
      for (int cf = 0; cf < 4; ++cf) s[rt][cf] = zero;
#pragma unroll
    for (int ks = 0; ks < 2; ++ks) {
#pragma unroll
      for (int cf = 0; cf < 4; ++cf) {
        bf16x8 kf = *reinterpret_cast<const bf16x8*>(&Ksh[ks][cf * 16 + r16][g4 * 8]);
#pragma unroll
        for (int rt = 0; rt < 2; ++rt)
          s[rt][cf] = __builtin_amdgcn_mfma_f32_16x16x32_bf16(qf[rt][ks], kf, s[rt][cf], 0, 0, 0);
      }
    }

    // ---- online softmax (rows = 4*g4+j within 16-row tile) ----
    float rm[2][4], rs[2][4], fct[2][4];
#pragma unroll
    for (int rt = 0; rt < 2; ++rt)
#pragma unroll
      for (int j = 0; j < 4; ++j)
        rm[rt][j] = fmaxf(fmaxf(s[rt][0][j], s[rt][1][j]), fmaxf(s[rt][2][j], s[rt][3][j]));
#pragma unroll
    for (int x = 1; x <= 8; x <<= 1)
#pragma unroll
      for (int rt = 0; rt < 2; ++rt)
#pragma unroll
        for (int j = 0; j < 4; ++j)
          rm[rt][j] = fmaxf(rm[rt][j], __shfl_xor(rm[rt][j], x, 64));
#pragma unroll
    for (int rt = 0; rt < 2; ++rt)
#pragma unroll
      for (int j = 0; j < 4; ++j) {
        float mn = fmaxf(m[rt][j], rm[rt][j]);
        fct[rt][j] = exp2f(m[rt][j] - mn);
        m[rt][j] = mn;
        rs[rt][j] = 0.f;
      }
#pragma unroll
    for (int rt = 0; rt < 2; ++rt)
#pragma unroll
      for (int cf = 0; cf < 4; ++cf)
#pragma unroll
        for (int j = 0; j < 4; ++j) {
          float p = exp2f(s[rt][cf][j] - m[rt][j]);
          s[rt][cf][j] = p;
          rs[rt][j] += p;
        }
#pragma unroll
    for (int x = 1; x <= 8; x <<= 1)
#pragma unroll
      for (int rt = 0; rt < 2; ++rt)
#pragma unroll
        for (int j = 0; j < 4; ++j)
          rs[rt][j] += __shfl_xor(rs[rt][j], x, 64);
#pragma unroll
    for (int rt = 0; rt < 2; ++rt)
#pragma unroll
      for (int j = 0; j < 4; ++j)
        l[rt][j] = l[rt][j] * fct[rt][j] + rs[rt][j];
#pragma unroll
    for (int rt = 0; rt < 2; ++rt)
#pragma unroll
      for (int cf = 0; cf < 4; ++cf)
#pragma unroll
        for (int j = 0; j < 4; ++j)
          o[rt][cf][j] *= fct[rt][j];

    // ---- P -> bf16 -> per-wave LDS (C-layout write, A-layout read) ----
#pragma unroll
    for (int rt = 0; rt < 2; ++rt)
#pragma unroll
      for (int cf = 0; cf < 4; ++cf)
#pragma unroll
        for (int j = 0; j < 4; ++j)
          Psh[w][cf >> 1][rt * 16 + g4 * 4 + j][(cf & 1) * 16 + r16] = f2bf(s[rt][cf][j]);

    // ---- O += P V ----
#pragma unroll
    for (int ks = 0; ks < 2; ++ks) {
      bf16x8 pf[2];
#pragma unroll
      for (int rt = 0; rt < 2; ++rt)
        pf[rt] = *reinterpret_cast<const bf16x8*>(&Psh[w][ks][rt * 16 + r16][g4 * 8]);
#pragma unroll
      for (int cf = 0; cf < 4; ++cf) {
        bf16x8 vf = *reinterpret_cast<const bf16x8*>(&Vsh[ks][cf * 16 + r16][g4 * 8]);
#pragma unroll
        for (int rt = 0; rt < 2; ++rt)
          o[rt][cf] = __builtin_amdgcn_mfma_f32_16x16x32_bf16(pf[rt], vf, o[rt][cf], 0, 0, 0);
      }
    }
  }

  // ---- normalize + store [b, s, h*64+d] fp32 ----
  int b = bh >> 4, h = bh & 15;
#pragma unroll
  for (int rt = 0; rt < 2; ++rt) {
    float inv[4];
#pragma unroll
    for (int j = 0; j < 4; ++j) inv[j] = 1.0f / l[rt][j];
#pragma unroll
    for (int cf = 0; cf < 4; ++cf) {
      int d = cf * 16 + r16;
#pragma unroll
      for (int j = 0; j < 4; ++j) {
        int qs = qt * 128 + w * 32 + rt * 16 + g4 * 4 + j;
        out[(size_t)(b * 2048 + qs) * 1024 + h * 64 + d] = o[rt][cf][j] * inv[j];
      }
    }
  }
}

extern "C" void kernel_launch(void* const* d_in, const int* in_sizes, int n_in,
                              void* d_out, int out_size, void* d_ws, size_t ws_size,
                              hipStream_t stream) {
  const float* hs = (const float*)d_in[0];
  const float* Wq = (const float*)d_in[1];
  const float* bq = (const float*)d_in[2];
  const float* Wk = (const float*)d_in[3];
  const float* bk = (const float*)d_in[4];
  const float* Wv = (const float*)d_in[5];
  const float* bv = (const float*)d_in[6];
  float* out = (float*)d_out;

  // workspace layout (bf16 as u16)
  u16* Xb  = (u16*)d_ws;                 // 8192*1024
  u16* Wtq = Xb  + 8192 * 1024;          // 1024*1024 each
  u16* Wtk = Wtq + 1024 * 1024;
  u16* Wtv = Wtk + 1024 * 1024;
  u16* Qb  = Wtv + 1024 * 1024;          // 64*2048*64 each ([b,h,s,d])
  u16* Kb  = Qb  + 64 * 2048 * 64;
  u16* Vb  = Kb  + 64 * 2048 * 64;

  k_cvtX<<<8192, 256, 0, stream>>>(hs, Xb);
  k_cvtW<<<dim3(16, 16, 3), 256, 0, stream>>>(Wq, Wk, Wv, Wtq, Wtk, Wtv);
  k_qkv<<<dim3(8, 64, 3), 256, 0, stream>>>(Xb, Wtq, Wtk, Wtv, bq, bk, bv, Qb, Kb, Vb);
  k_attn<<<dim3(1024), 256, 0, stream>>>(Qb, Kb, Vb, out);
}

// Round 5
// 567.893 us; speedup vs baseline: 1.0455x; 1.0455x over previous
//
#include <hip/hip_runtime.h>
#include <hip/hip_bf16.h>

typedef unsigned short u16;
typedef __attribute__((ext_vector_type(8))) __bf16 bf16x8;
typedef __attribute__((ext_vector_type(4))) float f32x4;

#define LOG2E 1.44269504088896340736f

__device__ __forceinline__ u16 f2bf(float f) {
  union { float f; unsigned u; } v; v.f = f;
  unsigned r = v.u + 0x7fffu + ((v.u >> 16) & 1u);
  return (u16)(r >> 16);
}

// ---------------- kernel: hidden_states fp32 -> bf16 ----------------
__global__ __launch_bounds__(256) void k_cvtX(const float* __restrict__ x,
                                              u16* __restrict__ xb) {
  int i = (blockIdx.x * 256 + threadIdx.x) * 4;
  float4 v = *reinterpret_cast<const float4*>(x + i);
  ushort4 o;
  o.x = f2bf(v.x); o.y = f2bf(v.y); o.z = f2bf(v.z); o.w = f2bf(v.w);
  *reinterpret_cast<ushort4*>(xb + i) = o;
}

// ---------------- kernel: W fp32 [K][N] -> Wt bf16 [N][K] ----------------
__global__ __launch_bounds__(256) void k_cvtW(const float* __restrict__ Wq,
                                              const float* __restrict__ Wk,
                                              const float* __restrict__ Wv,
                                              u16* __restrict__ Wtq,
                                              u16* __restrict__ Wtk,
                                              u16* __restrict__ Wtv) {
  const float* W = blockIdx.z == 0 ? Wq : (blockIdx.z == 1 ? Wk : Wv);
  u16* Wt = blockIdx.z == 0 ? Wtq : (blockIdx.z == 1 ? Wtk : Wtv);
  __shared__ u16 t[64][65];
  int n0 = blockIdx.x * 64, k0 = blockIdx.y * 64;
  int tid = threadIdx.x;
#pragma unroll
  for (int it = 0; it < 4; ++it) {
    int idx = it * 256 + tid;
    int r = idx >> 4, c = (idx & 15) * 4;
    float4 v = *reinterpret_cast<const float4*>(W + (size_t)(k0 + r) * 1024 + n0 + c);
    t[r][c] = f2bf(v.x); t[r][c + 1] = f2bf(v.y);
    t[r][c + 2] = f2bf(v.z); t[r][c + 3] = f2bf(v.w);
  }
  __syncthreads();
#pragma unroll
  for (int it = 0; it < 4; ++it) {
    int idx = it * 256 + tid;
    int r = idx >> 4, c = (idx & 15) * 4;
    ushort4 o;
    o.x = t[c][r]; o.y = t[c + 1][r]; o.z = t[c + 2][r]; o.w = t[c + 3][r];
    *reinterpret_cast<ushort4*>(Wt + (size_t)(n0 + r) * 1024 + k0 + c) = o;
  }
}

// ---------------- kernel: QKV projection GEMM ----------------
// R1-proven reg-staged structure + bijective XCD-aware swizzle.
__global__ __launch_bounds__(256) void k_qkv(
    const u16* __restrict__ Xb,
    const u16* __restrict__ Wtq, const u16* __restrict__ Wtk, const u16* __restrict__ Wtv,
    const float* __restrict__ bq, const float* __restrict__ bk, const float* __restrict__ bv,
    u16* __restrict__ Qb, u16* __restrict__ Kb, u16* __restrict__ Vb) {
  int z = blockIdx.z;
  const u16* Wt = z == 0 ? Wtq : (z == 1 ? Wtk : Wtv);
  const float* bias = z == 0 ? bq : (z == 1 ? bk : bv);
  u16* Out = z == 0 ? Qb : (z == 1 ? Kb : Vb);
  float scale = z == 0 ? 0.125f * LOG2E : 1.0f;

  // XCD-aware swizzle of the 512-block x-y plane (512 % 8 == 0, bijective)
  int lin = blockIdx.y * 8 + blockIdx.x;
  int swz = (lin & 7) * 64 + (lin >> 3);
  int bx = swz & 7, by = swz >> 3;
  int m0 = by * 128, n0 = bx * 128;

  __shared__ u16 Ash[128 * 32];   // [m][k], 64B rows -> conflict-free b128 frags
  __shared__ u16 Bsh[128 * 32];   // [n][k]

  int tid = threadIdx.x;
  int w = tid >> 6, lane = tid & 63;
  int r16 = lane & 15, g4 = lane >> 4;
  int wm = w >> 1, wn = w & 1;

  f32x4 zero = {0.f, 0.f, 0.f, 0.f};
  f32x4 acc[4][4];
#pragma unroll
  for (int i = 0; i < 4; ++i)
#pragma unroll
    for (int j = 0; j < 4; ++j) acc[i][j] = zero;

  uint4 ar[2], br[2];
#pragma unroll
  for (int c = 0; c < 2; ++c) {           // prefetch kt=0
    int idx = c * 256 + tid;
    int row = idx >> 2, c4 = idx & 3;
    ar[c] = *reinterpret_cast<const uint4*>(Xb + (size_t)(m0 + row) * 1024 + c4 * 8);
    br[c] = *reinterpret_cast<const uint4*>(Wt + (size_t)(n0 + row) * 1024 + c4 * 8);
  }

  for (int kt = 0; kt < 32; ++kt) {
    __syncthreads();
#pragma unroll
    for (int c = 0; c < 2; ++c) {
      int idx = c * 256 + tid;
      int row = idx >> 2, c4 = idx & 3;
      *reinterpret_cast<uint4*>(Ash + row * 32 + c4 * 8) = ar[c];
      *reinterpret_cast<uint4*>(Bsh + row * 32 + c4 * 8) = br[c];
    }
    __syncthreads();
    if (kt < 31) {                        // prefetch next K-tile under MFMA
      int k0n = (kt + 1) * 32;
#pragma unroll
      for (int c = 0; c < 2; ++c) {
        int idx = c * 256 + tid;
        int row = idx >> 2, c4 = idx & 3;
        ar[c] = *reinterpret_cast<const uint4*>(Xb + (size_t)(m0 + row) * 1024 + k0n + c4 * 8);
        br[c] = *reinterpret_cast<const uint4*>(Wt + (size_t)(n0 + row) * 1024 + k0n + c4 * 8);
      }
    }
    bf16x8 af[4], bfr[4];
#pragma unroll
    for (int mi = 0; mi < 4; ++mi)
      af[mi] = *reinterpret_cast<const bf16x8*>(Ash + (wm * 64 + mi * 16 + r16) * 32 + g4 * 8);
#pragma unroll
    for (int ni = 0; ni < 4; ++ni)
      bfr[ni] = *reinterpret_cast<const bf16x8*>(Bsh + (wn * 64 + ni * 16 + r16) * 32 + g4 * 8);
#pragma unroll
    for (int mi = 0; mi < 4; ++mi)
#pragma unroll
      for (int ni = 0; ni < 4; ++ni)
        acc[mi][ni] = __builtin_amdgcn_mfma_f32_16x16x32_bf16(af[mi], bfr[ni], acc[mi][ni], 0, 0, 0);
  }

  // epilogue: +bias, *scale, bf16, scatter into [b,h,s,d]
#pragma unroll
  for (int ni = 0; ni < 4; ++ni) {
    int n = n0 + wn * 64 + ni * 16 + r16;
    float bv_ = bias[n];
    int h = n >> 6, d = n & 63;
#pragma unroll
    for (int mi = 0; mi < 4; ++mi) {
#pragma unroll
      for (int j = 0; j < 4; ++j) {
        int mrow = m0 + wm * 64 + mi * 16 + g4 * 4 + j;
        int b = mrow >> 11, s = mrow & 2047;
        float val = (acc[mi][ni][j] + bv_) * scale;
        Out[(size_t)((b * 16 + h) * 2048 + s) * 64 + d] = f2bf(val);
      }
    }
  }
}

// ---------------- kernel: flash attention ----------------
// R1-proven structure; single change: defer-max rescale skip (THR=8, exp2
// domain) — exact math when skipped (P <= 2^8, same P in numer and denom).
__global__ __launch_bounds__(256) void k_attn(
    const u16* __restrict__ Qb, const u16* __restrict__ Kb,
    const u16* __restrict__ Vb, float* __restrict__ out) {
  int bh = blockIdx.x >> 4, qt = blockIdx.x & 15;
  const u16* Qp = Qb + (size_t)bh * 2048 * 64 + qt * 128 * 64;
  const u16* Kp = Kb + (size_t)bh * 2048 * 64;
  const u16* Vp = Vb + (size_t)bh * 2048 * 64;

  int tid = threadIdx.x;
  int w = tid >> 6, lane = tid & 63;
  int r16 = lane & 15, g4 = lane >> 4;

  __shared__ u16 Ksh[2][64][32];        // [d-half][key][d%32]
  __shared__ u16 Vsh[2][64][32];        // [key-half][d][key%32] (V^T)
  __shared__ u16 Psh[4][2][32][32];     // [wave][key-half][q][key%32]

  bf16x8 qf[2][2];                      // Q in registers, pre-scaled
#pragma unroll
  for (int rt = 0; rt < 2; ++rt)
#pragma unroll
    for (int ks = 0; ks < 2; ++ks)
      qf[rt][ks] = *reinterpret_cast<const bf16x8*>(
          Qp + (w * 32 + rt * 16 + r16) * 64 + ks * 32 + g4 * 8);

  f32x4 zero = {0.f, 0.f, 0.f, 0.f};
  f32x4 o[2][4];
  float m[2][4], l[2][4];
#pragma unroll
  for (int rt = 0; rt < 2; ++rt) {
#pragma unroll
    for (int cf = 0; cf < 4; ++cf) o[rt][cf] = zero;
#pragma unroll
    for (int j = 0; j < 4; ++j) { m[rt][j] = -1e30f; l[rt][j] = 0.f; }
  }

  uint4 kr[2], vr[2];
#pragma unroll
  for (int c = 0; c < 2; ++c) {         // prefetch kt=0
    int idx = c * 256 + tid;
    int c4 = idx & 3, key = (idx >> 2) & 63, ks = idx >> 8;
    kr[c] = *reinterpret_cast<const uint4*>(Kp + key * 64 + ks * 32 + c4 * 8);
    int dc = c * 4 + w;
    vr[c] = *reinterpret_cast<const uint4*>(Vp + lane * 64 + dc * 8);
  }

  for (int kt = 0; kt < 32; ++kt) {
    __syncthreads();
#pragma unroll
    for (int c = 0; c < 2; ++c) {       // stage K (b128) + V transposed (b16 x8)
      int idx = c * 256 + tid;
      int c4 = idx & 3, key = (idx >> 2) & 63, ks = idx >> 8;
      *reinterpret_cast<uint4*>(&Ksh[ks][key][c4 * 8]) = kr[c];
      int dc = c * 4 + w;
      const u16* pv = reinterpret_cast<const u16*>(&vr[c]);
#pragma unroll
      for (int i = 0; i < 8; ++i)
        Vsh[lane >> 5][dc * 8 + i][lane & 31] = pv[i];
    }
    __syncthreads();
    if (kt < 31) {                      // prefetch next tile under compute
      int key0 = (kt + 1) * 64;
#pragma unroll
      for (int c = 0; c < 2; ++c) {
        int idx = c * 256 + tid;
        int c4 = idx & 3, key = (idx >> 2) & 63, ks = idx >> 8;
        kr[c] = *reinterpret_cast<const uint4*>(Kp + (key0 + key) * 64 + ks * 32 + c4 * 8);
        int dc = c * 4 + w;
        vr[c] = *reinterpret_cast<const uint4*>(Vp + (key0 + lane) * 64 + dc * 8);
      }
    }

    // ---- scores: S = Q K^T (exp2 domain via pre-scaled Q) ----
    f32x4 s[2][4];
#pragma unroll
    for (int rt = 0; rt < 2; ++rt)
#pragma unroll
      for (int cf = 0; cf < 4; ++cf) s[rt][cf] = zero;
#pragma unroll
    for (int ks = 0; ks < 2; ++ks) {
#pragma unroll
      for (int cf = 0; cf < 4; ++cf) {
        bf16x8 kf = *reinterpret_cast<const bf16x8*>(&Ksh[ks][cf * 16 + r16][g4 * 8]);
#pragma unroll
        for (int rt = 0; rt < 2; ++rt)
          s[rt][cf] = __builtin_amdgcn_mfma_f32_16x16x32_bf16(qf[rt][ks], kf, s[rt][cf], 0, 0, 0);
      }
    }

    // ---- row max (butterfly over the 16 key-lanes) ----
    float rm[2][4];
#pragma unroll
    for (int rt = 0; rt < 2; ++rt)
#pragma unroll
      for (int j = 0; j < 4; ++j)
        rm[rt][j] = fmaxf(fmaxf(s[rt][0][j], s[rt][1][j]), fmaxf(s[rt][2][j], s[rt][3][j]));
#pragma unroll
    for (int x = 1; x <= 8; x <<= 1)
#pragma unroll
      for (int rt = 0; rt < 2; ++rt)
#pragma unroll
        for (int j = 0; j < 4; ++j)
          rm[rt][j] = fmaxf(rm[rt][j], __shfl_xor(rm[rt][j], x, 64));

    // ---- defer-max: rescale only when max grew past threshold ----
    bool need = false;
#pragma unroll
    for (int rt = 0; rt < 2; ++rt)
#pragma unroll
      for (int j = 0; j < 4; ++j) need |= rm[rt][j] > m[rt][j] + 8.0f;
    if (__any((int)need)) {
      float fct[2][4];
#pragma unroll
      for (int rt = 0; rt < 2; ++rt)
#pragma unroll
        for (int j = 0; j < 4; ++j) {
          float mn = fmaxf(m[rt][j], rm[rt][j]);
          fct[rt][j] = exp2f(m[rt][j] - mn);
          m[rt][j] = mn;
          l[rt][j] *= fct[rt][j];
        }
#pragma unroll
      for (int rt = 0; rt < 2; ++rt)
#pragma unroll
        for (int cf = 0; cf < 4; ++cf)
#pragma unroll
          for (int j = 0; j < 4; ++j)
            o[rt][cf][j] *= fct[rt][j];
    }

    // ---- P = exp2(s - m), accumulate row-sum, store bf16 P (R1 layout) ----
    float rs[2][4];
#pragma unroll
    for (int rt = 0; rt < 2; ++rt)
#pragma unroll
      for (int j = 0; j < 4; ++j) rs[rt][j] = 0.f;
#pragma unroll
    for (int rt = 0; rt < 2; ++rt)
#pragma unroll
      for (int cf = 0; cf < 4; ++cf)
#pragma unroll
        for (int j = 0; j < 4; ++j) {
          float p = exp2f(s[rt][cf][j] - m[rt][j]);
          rs[rt][j] += p;
          Psh[w][cf >> 1][rt * 16 + g4 * 4 + j][(cf & 1) * 16 + r16] = f2bf(p);
        }
#pragma unroll
    for (int x = 1; x <= 8; x <<= 1)
#pragma unroll
      for (int rt = 0; rt < 2; ++rt)
#pragma unroll
        for (int j = 0; j < 4; ++j)
          rs[rt][j] += __shfl_xor(rs[rt][j], x, 64);
#pragma unroll
    for (int rt = 0; rt < 2; ++rt)
#pragma unroll
      for (int j = 0; j < 4; ++j)
        l[rt][j] += rs[rt][j];

    // ---- O += P V ----
#pragma unroll
    for (int ks = 0; ks < 2; ++ks) {
      bf16x8 pf[2];
#pragma unroll
      for (int rt = 0; rt < 2; ++rt)
        pf[rt] = *reinterpret_cast<const bf16x8*>(&Psh[w][ks][rt * 16 + r16][g4 * 8]);
#pragma unroll
      for (int cf = 0; cf < 4; ++cf) {
        bf16x8 vf = *reinterpret_cast<const bf16x8*>(&Vsh[ks][cf * 16 + r16][g4 * 8]);
#pragma unroll
        for (int rt = 0; rt < 2; ++rt)
          o[rt][cf] = __builtin_amdgcn_mfma_f32_16x16x32_bf16(pf[rt], vf, o[rt][cf], 0, 0, 0);
      }
    }
  }

  // ---- normalize + store [b, s, h*64+d] fp32 ----
  int b = bh >> 4, h = bh & 15;
#pragma unroll
  for (int rt = 0; rt < 2; ++rt) {
    float inv[4];
#pragma unroll
    for (int j = 0; j < 4; ++j) inv[j] = 1.0f / l[rt][j];
#pragma unroll
    for (int cf = 0; cf < 4; ++cf) {
      int d = cf * 16 + r16;
#pragma unroll
      for (int j = 0; j < 4; ++j) {
        int qs = qt * 128 + w * 32 + rt * 16 + g4 * 4 + j;
        out[(size_t)(b * 2048 + qs) * 1024 + h * 64 + d] = o[rt][cf][j] * inv[j];
      }
    }
  }
}

extern "C" void kernel_launch(void* const* d_in, const int* in_sizes, int n_in,
                              void* d_out, int out_size, void* d_ws, size_t ws_size,
                              hipStream_t stream) {
  const float* hs = (const float*)d_in[0];
  const float* Wq = (const float*)d_in[1];
  const float* bq = (const float*)d_in[2];
  const float* Wk = (const float*)d_in[3];
  const float* bk = (const float*)d_in[4];
  const float* Wv = (const float*)d_in[5];
  const float* bv = (const float*)d_in[6];
  float* out = (float*)d_out;

  u16* Xb  = (u16*)d_ws;                 // 8192*1024
  u16* Wtq = Xb  + 8192 * 1024;
  u16* Wtk = Wtq + 1024 * 1024;
  u16* Wtv = Wtk + 1024 * 1024;
  u16* Qb  = Wtv + 1024 * 1024;
  u16* Kb  = Qb  + 64 * 2048 * 64;
  u16* Vb  = Kb  + 64 * 2048 * 64;

  k_cvtX<<<8192, 256, 0, stream>>>(hs, Xb);
  k_cvtW<<<dim3(16, 16, 3), 256, 0, stream>>>(Wq, Wk, Wv, Wtq, Wtk, Wtv);
  k_qkv<<<dim3(8, 64, 3), 256, 0, stream>>>(Xb, Wtq, Wtk, Wtv, bq, bk, bv, Qb, Kb, Vb);
  k_attn<<<dim3(1024), 256, 0, stream>>>(Qb, Kb, Vb, out);
}

// Round 6
// 405.396 us; speedup vs baseline: 1.4646x; 1.4008x over previous
//
#include <hip/hip_runtime.h>
#include <hip/hip_bf16.h>

typedef unsigned short u16;
typedef __attribute__((ext_vector_type(8))) __bf16 bf16x8;
typedef __attribute__((ext_vector_type(4))) float f32x4;

#define LOG2E 1.44269504088896340736f

__device__ __forceinline__ u16 f2bf(float f) {
  union { float f; unsigned u; } v; v.f = f;
  unsigned r = v.u + 0x7fffu + ((v.u >> 16) & 1u);
  return (u16)(r >> 16);
}

// async global->LDS, 16B per lane; lds base wave-uniform, HW adds lane*16.
__device__ __forceinline__ void gl_lds16(const u16* g, u16* l) {
  __builtin_amdgcn_global_load_lds(
      (const __attribute__((address_space(1))) void*)g,
      (__attribute__((address_space(3))) void*)l, 16, 0, 0);
}

// ---------------- kernel: hidden_states fp32 -> bf16 ----------------
__global__ __launch_bounds__(256) void k_cvtX(const float* __restrict__ x,
                                              u16* __restrict__ xb) {
  int i = (blockIdx.x * 256 + threadIdx.x) * 4;
  float4 v = *reinterpret_cast<const float4*>(x + i);
  ushort4 o;
  o.x = f2bf(v.x); o.y = f2bf(v.y); o.z = f2bf(v.z); o.w = f2bf(v.w);
  *reinterpret_cast<ushort4*>(xb + i) = o;
}

// ---------------- kernel: W fp32 [K][N] -> Wt bf16 [N][K] ----------------
__global__ __launch_bounds__(256) void k_cvtW(const float* __restrict__ Wq,
                                              const float* __restrict__ Wk,
                                              const float* __restrict__ Wv,
                                              u16* __restrict__ Wtq,
                                              u16* __restrict__ Wtk,
                                              u16* __restrict__ Wtv) {
  const float* W = blockIdx.z == 0 ? Wq : (blockIdx.z == 1 ? Wk : Wv);
  u16* Wt = blockIdx.z == 0 ? Wtq : (blockIdx.z == 1 ? Wtk : Wtv);
  __shared__ u16 t[64][65];
  int n0 = blockIdx.x * 64, k0 = blockIdx.y * 64;
  int tid = threadIdx.x;
#pragma unroll
  for (int it = 0; it < 4; ++it) {
    int idx = it * 256 + tid;
    int r = idx >> 4, c = (idx & 15) * 4;
    float4 v = *reinterpret_cast<const float4*>(W + (size_t)(k0 + r) * 1024 + n0 + c);
    t[r][c] = f2bf(v.x); t[r][c + 1] = f2bf(v.y);
    t[r][c + 2] = f2bf(v.z); t[r][c + 3] = f2bf(v.w);
  }
  __syncthreads();
#pragma unroll
  for (int it = 0; it < 4; ++it) {
    int idx = it * 256 + tid;
    int r = idx >> 4, c = (idx & 15) * 4;
    ushort4 o;
    o.x = t[c][r]; o.y = t[c + 1][r]; o.z = t[c + 2][r]; o.w = t[c + 3][r];
    *reinterpret_cast<ushort4*>(Wt + (size_t)(n0 + r) * 1024 + k0 + c) = o;
  }
}

// ---------------- kernel: QKV projection GEMM ----------------
// SINGLE CHANGE vs R5: staging via global_load_lds width-16 (m97 pattern).
// Layout map verified: lane L of (wave w, issue c) -> row (w*2+c)*16+(L>>2),
// cols (L&3)*8..+7; LDS dest = base(w,c) + L*16B = Ash[row*32 + col] exactly.
__global__ __launch_bounds__(256) void k_qkv(
    const u16* __restrict__ Xb,
    const u16* __restrict__ Wtq, const u16* __restrict__ Wtk, const u16* __restrict__ Wtv,
    const float* __restrict__ bq, const float* __restrict__ bk, const float* __restrict__ bv,
    u16* __restrict__ Qb, u16* __restrict__ Kb, u16* __restrict__ Vb) {
  int z = blockIdx.z;
  const u16* Wt = z == 0 ? Wtq : (z == 1 ? Wtk : Wtv);
  const float* bias = z == 0 ? bq : (z == 1 ? bk : bv);
  u16* Out = z == 0 ? Qb : (z == 1 ? Kb : Vb);
  float scale = z == 0 ? 0.125f * LOG2E : 1.0f;

  // XCD-aware swizzle of the 512-block x-y plane (512 % 8 == 0, bijective)
  int lin = blockIdx.y * 8 + blockIdx.x;
  int swz = (lin & 7) * 64 + (lin >> 3);
  int bx = swz & 7, by = swz >> 3;
  int m0 = by * 128, n0 = bx * 128;

  __shared__ u16 Ash[128 * 32];   // [m][k], 64B rows -> conflict-free b128 frags
  __shared__ u16 Bsh[128 * 32];   // [n][k]

  int tid = threadIdx.x;
  int w = tid >> 6, lane = tid & 63;
  int r16 = lane & 15, g4 = lane >> 4;
  int wm = w >> 1, wn = w & 1;

  // gload source/dest for this thread (2 issues for A, 2 for B per wave)
  const u16* Ag[2]; const u16* Bg[2]; u16* Al[2]; u16* Bl[2];
#pragma unroll
  for (int c = 0; c < 2; ++c) {
    int row = (w * 2 + c) * 16 + (lane >> 2);
    int col8 = (lane & 3) * 8;
    Ag[c] = Xb + (size_t)(m0 + row) * 1024 + col8;
    Bg[c] = Wt + (size_t)(n0 + row) * 1024 + col8;
    Al[c] = Ash + (w * 2 + c) * 512;
    Bl[c] = Bsh + (w * 2 + c) * 512;
  }

  f32x4 zero = {0.f, 0.f, 0.f, 0.f};
  f32x4 acc[4][4];
#pragma unroll
  for (int i = 0; i < 4; ++i)
#pragma unroll
    for (int j = 0; j < 4; ++j) acc[i][j] = zero;

  for (int kt = 0; kt < 32; ++kt) {
    __syncthreads();                         // prev tile's ds_reads done
#pragma unroll
    for (int c = 0; c < 2; ++c) gl_lds16(Ag[c] + kt * 32, Al[c]);
#pragma unroll
    for (int c = 0; c < 2; ++c) gl_lds16(Bg[c] + kt * 32, Bl[c]);
    __syncthreads();                         // compiler drains vmcnt here

    bf16x8 af[4], bfr[4];
#pragma unroll
    for (int mi = 0; mi < 4; ++mi)
      af[mi] = *reinterpret_cast<const bf16x8*>(Ash + (wm * 64 + mi * 16 + r16) * 32 + g4 * 8);
#pragma unroll
    for (int ni = 0; ni < 4; ++ni)
      bfr[ni] = *reinterpret_cast<const bf16x8*>(Bsh + (wn * 64 + ni * 16 + r16) * 32 + g4 * 8);
#pragma unroll
    for (int mi = 0; mi < 4; ++mi)
#pragma unroll
      for (int ni = 0; ni < 4; ++ni)
        acc[mi][ni] = __builtin_amdgcn_mfma_f32_16x16x32_bf16(af[mi], bfr[ni], acc[mi][ni], 0, 0, 0);
  }

  // epilogue: +bias, *scale, bf16, scatter into [b,h,s,d]
#pragma unroll
  for (int ni = 0; ni < 4; ++ni) {
    int n = n0 + wn * 64 + ni * 16 + r16;
    float bv_ = bias[n];
    int h = n >> 6, d = n & 63;
#pragma unroll
    for (int mi = 0; mi < 4; ++mi) {
#pragma unroll
      for (int j = 0; j < 4; ++j) {
        int mrow = m0 + wm * 64 + mi * 16 + g4 * 4 + j;
        int b = mrow >> 11, s = mrow & 2047;
        float val = (acc[mi][ni][j] + bv_) * scale;
        Out[(size_t)((b * 16 + h) * 2048 + s) * 64 + d] = f2bf(val);
      }
    }
  }
}

// ---------------- kernel: flash attention ----------------
// BYTE-IDENTICAL to R5 (proven green): R1 structure + defer-max (THR=8).
__global__ __launch_bounds__(256) void k_attn(
    const u16* __restrict__ Qb, const u16* __restrict__ Kb,
    const u16* __restrict__ Vb, float* __restrict__ out) {
  int bh = blockIdx.x >> 4, qt = blockIdx.x & 15;
  const u16* Qp = Qb + (size_t)bh * 2048 * 64 + qt * 128 * 64;
  const u16* Kp = Kb + (size_t)bh * 2048 * 64;
  const u16* Vp = Vb + (size_t)bh * 2048 * 64;

  int tid = threadIdx.x;
  int w = tid >> 6, lane = tid & 63;
  int r16 = lane & 15, g4 = lane >> 4;

  __shared__ u16 Ksh[2][64][32];        // [d-half][key][d%32]
  __shared__ u16 Vsh[2][64][32];        // [key-half][d][key%32] (V^T)
  __shared__ u16 Psh[4][2][32][32];     // [wave][key-half][q][key%32]

  bf16x8 qf[2][2];                      // Q in registers, pre-scaled
#pragma unroll
  for (int rt = 0; rt < 2; ++rt)
#pragma unroll
    for (int ks = 0; ks < 2; ++ks)
      qf[rt][ks] = *reinterpret_cast<const bf16x8*>(
          Qp + (w * 32 + rt * 16 + r16) * 64 + ks * 32 + g4 * 8);

  f32x4 zero = {0.f, 0.f, 0.f, 0.f};
  f32x4 o[2][4];
  float m[2][4], l[2][4];
#pragma unroll
  for (int rt = 0; rt < 2; ++rt) {
#pragma unroll
    for (int cf = 0; cf < 4; ++cf) o[rt][cf] = zero;
#pragma unroll
    for (int j = 0; j < 4; ++j) { m[rt][j] = -1e30f; l[rt][j] = 0.f; }
  }

  uint4 kr[2], vr[2];
#pragma unroll
  for (int c = 0; c < 2; ++c) {         // prefetch kt=0
    int idx = c * 256 + tid;
    int c4 = idx & 3, key = (idx >> 2) & 63, ks = idx >> 8;
    kr[c] = *reinterpret_cast<const uint4*>(Kp + key * 64 + ks * 32 + c4 * 8);
    int dc = c * 4 + w;
    vr[c] = *reinterpret_cast<const uint4*>(Vp + lane * 64 + dc * 8);
  }

  for (int kt = 0; kt < 32; ++kt) {
    __syncthreads();
#pragma unroll
    for (int c = 0; c < 2; ++c) {       // stage K (b128) + V transposed (b16 x8)
      int idx = c * 256 + tid;
      int c4 = idx & 3, key = (idx >> 2) & 63, ks = idx >> 8;
      *reinterpret_cast<uint4*>(&Ksh[ks][key][c4 * 8]) = kr[c];
      int dc = c * 4 + w;
      const u16* pv = reinterpret_cast<const u16*>(&vr[c]);
#pragma unroll
      for (int i = 0; i < 8; ++i)
        Vsh[lane >> 5][dc * 8 + i][lane & 31] = pv[i];
    }
    __syncthreads();
    if (kt < 31) {                      // prefetch next tile under compute
      int key0 = (kt + 1) * 64;
#pragma unroll
      for (int c = 0; c < 2; ++c) {
        int idx = c * 256 + tid;
        int c4 = idx & 3, key = (idx >> 2) & 63, ks = idx >> 8;
        kr[c] = *reinterpret_cast<const uint4*>(Kp + (key0 + key) * 64 + ks * 32 + c4 * 8);
        int dc = c * 4 + w;
        vr[c] = *reinterpret_cast<const uint4*>(Vp + (key0 + lane) * 64 + dc * 8);
      }
    }

    // ---- scores: S = Q K^T (exp2 domain via pre-scaled Q) ----
    f32x4 s[2][4];
#pragma unroll
    for (int rt = 0; rt < 2; ++rt)
#pragma unroll
      for (int cf = 0; cf < 4; ++cf) s[rt][cf] = zero;
#pragma unroll
    for (int ks = 0; ks < 2; ++ks) {
#pragma unroll
      for (int cf = 0; cf < 4; ++cf) {
        bf16x8 kf = *reinterpret_cast<const bf16x8*>(&Ksh[ks][cf * 16 + r16][g4 * 8]);
#pragma unroll
        for (int rt = 0; rt < 2; ++rt)
          s[rt][cf] = __builtin_amdgcn_mfma_f32_16x16x32_bf16(qf[rt][ks], kf, s[rt][cf], 0, 0, 0);
      }
    }

    // ---- row max (butterfly over the 16 key-lanes) ----
    float rm[2][4];
#pragma unroll
    for (int rt = 0; rt < 2; ++rt)
#pragma unroll
      for (int j = 0; j < 4; ++j)
        rm[rt][j] = fmaxf(fmaxf(s[rt][0][j], s[rt][1][j]), fmaxf(s[rt][2][j], s[rt][3][j]));
#pragma unroll
    for (int x = 1; x <= 8; x <<= 1)
#pragma unroll
      for (int rt = 0; rt < 2; ++rt)
#pragma unroll
        for (int j = 0; j < 4; ++j)
          rm[rt][j] = fmaxf(rm[rt][j], __shfl_xor(rm[rt][j], x, 64));

    // ---- defer-max: rescale only when max grew past threshold ----
    bool need = false;
#pragma unroll
    for (int rt = 0; rt < 2; ++rt)
#pragma unroll
      for (int j = 0; j < 4; ++j) need |= rm[rt][j] > m[rt][j] + 8.0f;
    if (__any((int)need)) {
      float fct[2][4];
#pragma unroll
      for (int rt = 0; rt < 2; ++rt)
#pragma unroll
        for (int j = 0; j < 4; ++j) {
          float mn = fmaxf(m[rt][j], rm[rt][j]);
          fct[rt][j] = exp2f(m[rt][j] - mn);
          m[rt][j] = mn;
          l[rt][j] *= fct[rt][j];
        }
#pragma unroll
      for (int rt = 0; rt < 2; ++rt)
#pragma unroll
        for (int cf = 0; cf < 4; ++cf)
#pragma unroll
          for (int j = 0; j < 4; ++j)
            o[rt][cf][j] *= fct[rt][j];
    }

    // ---- P = exp2(s - m), accumulate row-sum, store bf16 P (R1 layout) ----
    float rs[2][4];
#pragma unroll
    for (int rt = 0; rt < 2; ++rt)
#pragma unroll
      for (int j = 0; j < 4; ++j) rs[rt][j] = 0.f;
#pragma unroll
    for (int rt = 0; rt < 2; ++rt)
#pragma unroll
      for (int cf = 0; cf < 4; ++cf)
#pragma unroll
        for (int j = 0; j < 4; ++j) {
          float p = exp2f(s[rt][cf][j] - m[rt][j]);
          rs[rt][j] += p;
          Psh[w][cf >> 1][rt * 16 + g4 * 4 + j][(cf & 1) * 16 + r16] = f2bf(p);
        }
#pragma unroll
    for (int x = 1; x <= 8; x <<= 1)
#pragma unroll
      for (int rt = 0; rt < 2; ++rt)
#pragma unroll
        for (int j = 0; j < 4; ++j)
          rs[rt][j] += __shfl_xor(rs[rt][j], x, 64);
#pragma unroll
    for (int rt = 0; rt < 2; ++rt)
#pragma unroll
      for (int j = 0; j < 4; ++j)
        l[rt][j] += rs[rt][j];

    // ---- O += P V ----
#pragma unroll
    for (int ks = 0; ks < 2; ++ks) {
      bf16x8 pf[2];
#pragma unroll
      for (int rt = 0; rt < 2; ++rt)
        pf[rt] = *reinterpret_cast<const bf16x8*>(&Psh[w][ks][rt * 16 + r16][g4 * 8]);
#pragma unroll
      for (int cf = 0; cf < 4; ++cf) {
        bf16x8 vf = *reinterpret_cast<const bf16x8*>(&Vsh[ks][cf * 16 + r16][g4 * 8]);
#pragma unroll
        for (int rt = 0; rt < 2; ++rt)
          o[rt][cf] = __builtin_amdgcn_mfma_f32_16x16x32_bf16(pf[rt], vf, o[rt][cf], 0, 0, 0);
      }
    }
  }

  // ---- normalize + store [b, s, h*64+d] fp32 ----
  int b = bh >> 4, h = bh & 15;
#pragma unroll
  for (int rt = 0; rt < 2; ++rt) {
    float inv[4];
#pragma unroll
    for (int j = 0; j < 4; ++j) inv[j] = 1.0f / l[rt][j];
#pragma unroll
    for (int cf = 0; cf < 4; ++cf) {
      int d = cf * 16 + r16;
#pragma unroll
      for (int j = 0; j < 4; ++j) {
        int qs = qt * 128 + w * 32 + rt * 16 + g4 * 4 + j;
        out[(size_t)(b * 2048 + qs) * 1024 + h * 64 + d] = o[rt][cf][j] * inv[j];
      }
    }
  }
}

extern "C" void kernel_launch(void* const* d_in, const int* in_sizes, int n_in,
                              void* d_out, int out_size, void* d_ws, size_t ws_size,
                              hipStream_t stream) {
  const float* hs = (const float*)d_in[0];
  const float* Wq = (const float*)d_in[1];
  const float* bq = (const float*)d_in[2];
  const float* Wk = (const float*)d_in[3];
  const float* bk = (const float*)d_in[4];
  const float* Wv = (const float*)d_in[5];
  const float* bv = (const float*)d_in[6];
  float* out = (float*)d_out;

  u16* Xb  = (u16*)d_ws;                 // 8192*1024
  u16* Wtq = Xb  + 8192 * 1024;
  u16* Wtk = Wtq + 1024 * 1024;
  u16* Wtv = Wtk + 1024 * 1024;
  u16* Qb  = Wtv + 1024 * 1024;
  u16* Kb  = Qb  + 64 * 2048 * 64;
  u16* Vb  = Kb  + 64 * 2048 * 64;

  k_cvtX<<<8192, 256, 0, stream>>>(hs, Xb);
  k_cvtW<<<dim3(16, 16, 3), 256, 0, stream>>>(Wq, Wk, Wv, Wtq, Wtk, Wtv);
  k_qkv<<<dim3(8, 64, 3), 256, 0, stream>>>(Xb, Wtq, Wtk, Wtv, bq, bk, bv, Qb, Kb, Vb);
  k_attn<<<dim3(1024), 256, 0, stream>>>(Qb, Kb, Vb, out);
}

// Round 7
// 322.863 us; speedup vs baseline: 1.8390x; 1.2556x over previous
//
#include <hip/hip_runtime.h>
#include <hip/hip_bf16.h>

typedef unsigned short u16;
typedef unsigned int u32;
typedef __attribute__((ext_vector_type(8))) __bf16 bf16x8;
typedef __attribute__((ext_vector_type(4))) float f32x4;
typedef __attribute__((ext_vector_type(4))) u32 u32x4;

#define LOG2E 1.44269504088896340736f

__device__ __forceinline__ u16 f2bf(float f) {
  union { float f; unsigned u; } v; v.f = f;
  unsigned r = v.u + 0x7fffu + ((v.u >> 16) & 1u);
  return (u16)(r >> 16);
}

// async global->LDS, 16B per lane; lds base wave-uniform, HW adds lane*16.
__device__ __forceinline__ void gl_lds16(const u16* g, u16* l) {
  __builtin_amdgcn_global_load_lds(
      (const __attribute__((address_space(1))) void*)g,
      (__attribute__((address_space(3))) void*)l, 16, 0, 0);
}

// ---------------- kernel: hidden_states fp32 -> bf16 ----------------
__global__ __launch_bounds__(256) void k_cvtX(const float* __restrict__ x,
                                              u16* __restrict__ xb) {
  int i = (blockIdx.x * 256 + threadIdx.x) * 4;
  float4 v = *reinterpret_cast<const float4*>(x + i);
  ushort4 o;
  o.x = f2bf(v.x); o.y = f2bf(v.y); o.z = f2bf(v.z); o.w = f2bf(v.w);
  *reinterpret_cast<ushort4*>(xb + i) = o;
}

// ---------------- kernel: W fp32 [K][N] -> Wt bf16 [N][K] ----------------
__global__ __launch_bounds__(256) void k_cvtW(const float* __restrict__ Wq,
                                              const float* __restrict__ Wk,
                                              const float* __restrict__ Wv,
                                              u16* __restrict__ Wtq,
                                              u16* __restrict__ Wtk,
                                              u16* __restrict__ Wtv) {
  const float* W = blockIdx.z == 0 ? Wq : (blockIdx.z == 1 ? Wk : Wv);
  u16* Wt = blockIdx.z == 0 ? Wtq : (blockIdx.z == 1 ? Wtk : Wtv);
  __shared__ u16 t[64][65];
  int n0 = blockIdx.x * 64, k0 = blockIdx.y * 64;
  int tid = threadIdx.x;
#pragma unroll
  for (int it = 0; it < 4; ++it) {
    int idx = it * 256 + tid;
    int r = idx >> 4, c = (idx & 15) * 4;
    float4 v = *reinterpret_cast<const float4*>(W + (size_t)(k0 + r) * 1024 + n0 + c);
    t[r][c] = f2bf(v.x); t[r][c + 1] = f2bf(v.y);
    t[r][c + 2] = f2bf(v.z); t[r][c + 3] = f2bf(v.w);
  }
  __syncthreads();
#pragma unroll
  for (int it = 0; it < 4; ++it) {
    int idx = it * 256 + tid;
    int r = idx >> 4, c = (idx & 15) * 4;
    ushort4 o;
    o.x = t[c][r]; o.y = t[c + 1][r]; o.z = t[c + 2][r]; o.w = t[c + 3][r];
    *reinterpret_cast<ushort4*>(Wt + (size_t)(n0 + r) * 1024 + k0 + c) = o;
  }
}

// ---------------- kernel: QKV projection GEMM ----------------
// BYTE-IDENTICAL to R6 (proven green): global_load_lds width-16 staging.
__global__ __launch_bounds__(256) void k_qkv(
    const u16* __restrict__ Xb,
    const u16* __restrict__ Wtq, const u16* __restrict__ Wtk, const u16* __restrict__ Wtv,
    const float* __restrict__ bq, const float* __restrict__ bk, const float* __restrict__ bv,
    u16* __restrict__ Qb, u16* __restrict__ Kb, u16* __restrict__ Vb) {
  int z = blockIdx.z;
  const u16* Wt = z == 0 ? Wtq : (z == 1 ? Wtk : Wtv);
  const float* bias = z == 0 ? bq : (z == 1 ? bk : bv);
  u16* Out = z == 0 ? Qb : (z == 1 ? Kb : Vb);
  float scale = z == 0 ? 0.125f * LOG2E : 1.0f;

  int lin = blockIdx.y * 8 + blockIdx.x;
  int swz = (lin & 7) * 64 + (lin >> 3);
  int bx = swz & 7, by = swz >> 3;
  int m0 = by * 128, n0 = bx * 128;

  __shared__ u16 Ash[128 * 32];
  __shared__ u16 Bsh[128 * 32];

  int tid = threadIdx.x;
  int w = tid >> 6, lane = tid & 63;
  int r16 = lane & 15, g4 = lane >> 4;
  int wm = w >> 1, wn = w & 1;

  const u16* Ag[2]; const u16* Bg[2]; u16* Al[2]; u16* Bl[2];
#pragma unroll
  for (int c = 0; c < 2; ++c) {
    int row = (w * 2 + c) * 16 + (lane >> 2);
    int col8 = (lane & 3) * 8;
    Ag[c] = Xb + (size_t)(m0 + row) * 1024 + col8;
    Bg[c] = Wt + (size_t)(n0 + row) * 1024 + col8;
    Al[c] = Ash + (w * 2 + c) * 512;
    Bl[c] = Bsh + (w * 2 + c) * 512;
  }

  f32x4 zero = {0.f, 0.f, 0.f, 0.f};
  f32x4 acc[4][4];
#pragma unroll
  for (int i = 0; i < 4; ++i)
#pragma unroll
    for (int j = 0; j < 4; ++j) acc[i][j] = zero;

  for (int kt = 0; kt < 32; ++kt) {
    __syncthreads();
#pragma unroll
    for (int c = 0; c < 2; ++c) gl_lds16(Ag[c] + kt * 32, Al[c]);
#pragma unroll
    for (int c = 0; c < 2; ++c) gl_lds16(Bg[c] + kt * 32, Bl[c]);
    __syncthreads();

    bf16x8 af[4], bfr[4];
#pragma unroll
    for (int mi = 0; mi < 4; ++mi)
      af[mi] = *reinterpret_cast<const bf16x8*>(Ash + (wm * 64 + mi * 16 + r16) * 32 + g4 * 8);
#pragma unroll
    for (int ni = 0; ni < 4; ++ni)
      bfr[ni] = *reinterpret_cast<const bf16x8*>(Bsh + (wn * 64 + ni * 16 + r16) * 32 + g4 * 8);
#pragma unroll
    for (int mi = 0; mi < 4; ++mi)
#pragma unroll
      for (int ni = 0; ni < 4; ++ni)
        acc[mi][ni] = __builtin_amdgcn_mfma_f32_16x16x32_bf16(af[mi], bfr[ni], acc[mi][ni], 0, 0, 0);
  }

#pragma unroll
  for (int ni = 0; ni < 4; ++ni) {
    int n = n0 + wn * 64 + ni * 16 + r16;
    float bv_ = bias[n];
    int h = n >> 6, d = n & 63;
#pragma unroll
    for (int mi = 0; mi < 4; ++mi) {
#pragma unroll
      for (int j = 0; j < 4; ++j) {
        int mrow = m0 + wm * 64 + mi * 16 + g4 * 4 + j;
        int b = mrow >> 11, s = mrow & 2047;
        float val = (acc[mi][ni][j] + bv_) * scale;
        Out[(size_t)((b * 16 + h) * 2048 + s) * 64 + d] = f2bf(val);
      }
    }
  }
}

// ---------------- kernel: flash attention (swapped QK^T) ----------------
// S^T = mfma(K, Q): each lane owns one q-row (r16), keys 16cf+4g4+r.
// Softmax: 15 local ops + 2 shfl per rt. P packed in registers as PV's
// B-operand (k-slot bijection pi(g,e)=4g+(e&3)+16(e>>2) applied to BOTH
// P packing and V^T staging columns). No P LDS round-trip.
__global__ __launch_bounds__(256) void k_attn(
    const u16* __restrict__ Qb, const u16* __restrict__ Kb,
    const u16* __restrict__ Vb, float* __restrict__ out) {
  int bh = blockIdx.x >> 4, qt = blockIdx.x & 15;
  const u16* Qp = Qb + (size_t)bh * 2048 * 64 + qt * 128 * 64;
  const u16* Kp = Kb + (size_t)bh * 2048 * 64;
  const u16* Vp = Vb + (size_t)bh * 2048 * 64;

  int tid = threadIdx.x;
  int w = tid >> 6, lane = tid & 63;
  int r16 = lane & 15, g4 = lane >> 4;

  __shared__ u16 Ksh[2][64][32];        // [d-half][key][d%32]
  __shared__ u16 Vsh[2][64][32];        // [key-half][d][pi-perm key%32]

  bf16x8 qf[2][2];                      // Q in registers, pre-scaled
#pragma unroll
  for (int rt = 0; rt < 2; ++rt)
#pragma unroll
    for (int ks = 0; ks < 2; ++ks)
      qf[rt][ks] = *reinterpret_cast<const bf16x8*>(
          Qp + (w * 32 + rt * 16 + r16) * 64 + ks * 32 + g4 * 8);

  f32x4 zero = {0.f, 0.f, 0.f, 0.f};
  f32x4 o[2][4];                        // O^T frag: row d = 16cf+4g4+j, col q = r16
  float m[2], l[2];
#pragma unroll
  for (int rt = 0; rt < 2; ++rt) {
#pragma unroll
    for (int cf = 0; cf < 4; ++cf) o[rt][cf] = zero;
    m[rt] = -1e30f; l[rt] = 0.f;
  }

  // V^T staging column for this thread's key (key32 = lane&31), permuted by pi
  int vks = lane >> 5;
  int vcc = ((lane >> 2) & 3) * 8 + ((lane >> 4) & 1) * 4 + (lane & 3);

  uint4 kr[2], vr[2];
#pragma unroll
  for (int c = 0; c < 2; ++c) {         // prefetch kt=0
    int idx = c * 256 + tid;
    int c4 = idx & 3, key = (idx >> 2) & 63, ks = idx >> 8;
    kr[c] = *reinterpret_cast<const uint4*>(Kp + key * 64 + ks * 32 + c4 * 8);
    int dc = c * 4 + w;
    vr[c] = *reinterpret_cast<const uint4*>(Vp + lane * 64 + dc * 8);
  }

  for (int kt = 0; kt < 32; ++kt) {
    __syncthreads();
#pragma unroll
    for (int c = 0; c < 2; ++c) {       // stage K (b128) + V^T (b16 x8, pi-perm)
      int idx = c * 256 + tid;
      int c4 = idx & 3, key = (idx >> 2) & 63, ks = idx >> 8;
      *reinterpret_cast<uint4*>(&Ksh[ks][key][c4 * 8]) = kr[c];
      int dc = c * 4 + w;
      const u16* pv = reinterpret_cast<const u16*>(&vr[c]);
#pragma unroll
      for (int i = 0; i < 8; ++i)
        Vsh[vks][dc * 8 + i][vcc] = pv[i];
    }
    __syncthreads();
    if (kt < 31) {                      // prefetch next tile under compute
      int key0 = (kt + 1) * 64;
#pragma unroll
      for (int c = 0; c < 2; ++c) {
        int idx = c * 256 + tid;
        int c4 = idx & 3, key = (idx >> 2) & 63, ks = idx >> 8;
        kr[c] = *reinterpret_cast<const uint4*>(Kp + (key0 + key) * 64 + ks * 32 + c4 * 8);
        int dc = c * 4 + w;
        vr[c] = *reinterpret_cast<const uint4*>(Vp + (key0 + lane) * 64 + dc * 8);
      }
    }

    // ---- S^T = K Q^T (exp2 domain): lane owns q-row r16, keys 16cf+4g4+j ----
    f32x4 s[2][4];
#pragma unroll
    for (int rt = 0; rt < 2; ++rt)
#pragma unroll
      for (int cf = 0; cf < 4; ++cf) s[rt][cf] = zero;
#pragma unroll
    for (int ks = 0; ks < 2; ++ks) {
#pragma unroll
      for (int cf = 0; cf < 4; ++cf) {
        bf16x8 kf = *reinterpret_cast<const bf16x8*>(&Ksh[ks][cf * 16 + r16][g4 * 8]);
#pragma unroll
        for (int rt = 0; rt < 2; ++rt)
          s[rt][cf] = __builtin_amdgcn_mfma_f32_16x16x32_bf16(kf, qf[rt][ks], s[rt][cf], 0, 0, 0);
      }
    }

    // ---- row max: 15 local fmax + 2 shfl over the 4 g4-copies ----
    float rm[2];
#pragma unroll
    for (int rt = 0; rt < 2; ++rt) {
      float a = fmaxf(fmaxf(s[rt][0][0], s[rt][0][1]), fmaxf(s[rt][0][2], s[rt][0][3]));
      float b2 = fmaxf(fmaxf(s[rt][1][0], s[rt][1][1]), fmaxf(s[rt][1][2], s[rt][1][3]));
      float c2 = fmaxf(fmaxf(s[rt][2][0], s[rt][2][1]), fmaxf(s[rt][2][2], s[rt][2][3]));
      float d2 = fmaxf(fmaxf(s[rt][3][0], s[rt][3][1]), fmaxf(s[rt][3][2], s[rt][3][3]));
      float r = fmaxf(fmaxf(a, b2), fmaxf(c2, d2));
      r = fmaxf(r, __shfl_xor(r, 16, 64));
      r = fmaxf(r, __shfl_xor(r, 32, 64));
      rm[rt] = r;
    }

    // ---- defer-max: rescale only when max grew past threshold ----
    bool need = (rm[0] > m[0] + 8.0f) || (rm[1] > m[1] + 8.0f);
    if (__any((int)need)) {
#pragma unroll
      for (int rt = 0; rt < 2; ++rt) {
        float mn = fmaxf(m[rt], rm[rt]);
        float fct = exp2f(m[rt] - mn);
        m[rt] = mn;
        l[rt] *= fct;
#pragma unroll
        for (int cf = 0; cf < 4; ++cf)
#pragma unroll
          for (int j = 0; j < 4; ++j)
            o[rt][cf][j] *= fct;
      }
    }

    // ---- P = exp2(s-m), row-sum, pack bf16 into PV B-frags (registers) ----
    u32x4 pw[2][2];                     // [rt][key-half], 8 bf16 each
#pragma unroll
    for (int rt = 0; rt < 2; ++rt) {
      float rsum = 0.f;
#pragma unroll
      for (int cf = 0; cf < 4; ++cf)
#pragma unroll
        for (int jp = 0; jp < 2; ++jp) {
          float p0 = exp2f(s[rt][cf][2 * jp] - m[rt]);
          float p1 = exp2f(s[rt][cf][2 * jp + 1] - m[rt]);
          rsum += p0 + p1;
          pw[rt][cf >> 1][2 * (cf & 1) + jp] =
              (u32)f2bf(p0) | ((u32)f2bf(p1) << 16);
        }
      rsum += __shfl_xor(rsum, 16, 64);
      rsum += __shfl_xor(rsum, 32, 64);
      l[rt] += rsum;
    }

    // ---- O^T += V^T P^T  (A = V^T from LDS, B = P^T from registers) ----
#pragma unroll
    for (int h = 0; h < 2; ++h) {
#pragma unroll
      for (int cf = 0; cf < 4; ++cf) {
        bf16x8 vf = *reinterpret_cast<const bf16x8*>(&Vsh[h][cf * 16 + r16][g4 * 8]);
#pragma unroll
        for (int rt = 0; rt < 2; ++rt)
          o[rt][cf] = __builtin_amdgcn_mfma_f32_16x16x32_bf16(
              vf, __builtin_bit_cast(bf16x8, pw[rt][h]), o[rt][cf], 0, 0, 0);
      }
    }
  }

  // ---- normalize + store: lane owns q-row r16, d = 16cf+4g4+j (float4) ----
  int b = bh >> 4, hh = bh & 15;
#pragma unroll
  for (int rt = 0; rt < 2; ++rt) {
    float inv = 1.0f / l[rt];
    int qs = qt * 128 + w * 32 + rt * 16 + r16;
    float* op = out + (size_t)(b * 2048 + qs) * 1024 + hh * 64 + g4 * 4;
#pragma unroll
    for (int cf = 0; cf < 4; ++cf) {
      float4 v4 = { o[rt][cf][0] * inv, o[rt][cf][1] * inv,
                    o[rt][cf][2] * inv, o[rt][cf][3] * inv };
      *reinterpret_cast<float4*>(op + cf * 16) = v4;
    }
  }
}

extern "C" void kernel_launch(void* const* d_in, const int* in_sizes, int n_in,
                              void* d_out, int out_size, void* d_ws, size_t ws_size,
                              hipStream_t stream) {
  const float* hs = (const float*)d_in[0];
  const float* Wq = (const float*)d_in[1];
  const float* bq = (const float*)d_in[2];
  const float* Wk = (const float*)d_in[3];
  const float* bk = (const float*)d_in[4];
  const float* Wv = (const float*)d_in[5];
  const float* bv = (const float*)d_in[6];
  float* out = (float*)d_out;

  u16* Xb  = (u16*)d_ws;                 // 8192*1024
  u16* Wtq = Xb  + 8192 * 1024;
  u16* Wtk = Wtq + 1024 * 1024;
  u16* Wtv = Wtk + 1024 * 1024;
  u16* Qb  = Wtv + 1024 * 1024;
  u16* Kb  = Qb  + 64 * 2048 * 64;
  u16* Vb  = Kb  + 64 * 2048 * 64;

  k_cvtX<<<8192, 256, 0, stream>>>(hs, Xb);
  k_cvtW<<<dim3(16, 16, 3), 256, 0, stream>>>(Wq, Wk, Wv, Wtq, Wtk, Wtv);
  k_qkv<<<dim3(8, 64, 3), 256, 0, stream>>>(Xb, Wtq, Wtk, Wtv, bq, bk, bv, Qb, Kb, Vb);
  k_attn<<<dim3(1024), 256, 0, stream>>>(Qb, Kb, Vb, out);
}